// Round 8
// baseline (282.461 us; speedup 1.0000x reference)
//
#include <hip/hip_runtime.h>
#include <hip/hip_fp16.h>

#define EPS 1e-5f

// ---------------------------------------------------------------------------
// K1: in-degree histogram (edges only; self-loop folded in as +1 later)
__global__ void count_kernel(const int* __restrict__ col, int* __restrict__ counts, int E) {
    int e = blockIdx.x * blockDim.x + threadIdx.x;
    if (e < E) atomicAdd(&counts[col[e]], 1);
}

// ---------------------------------------------------------------------------
// K2a: per-block (256 counts each) partial sums
__global__ void scan_reduce(const int* __restrict__ counts, int* __restrict__ blockSums, int N) {
    __shared__ int red[256];
    int i = blockIdx.x * 256 + threadIdx.x;
    red[threadIdx.x] = (i < N) ? counts[i] : 0;
    __syncthreads();
    for (int d = 128; d > 0; d >>= 1) {
        if (threadIdx.x < d) red[threadIdx.x] += red[threadIdx.x + d];
        __syncthreads();
    }
    if (threadIdx.x == 0) blockSums[blockIdx.x] = red[0];
}

// K2b: single-block exclusive scan over the (<=1024) block sums; writes offsets[N]=total
__global__ void scan_blocksums(int* __restrict__ blockSums, int* __restrict__ blockOffs,
                               int nb, int* __restrict__ offsets, int N) {
    __shared__ int s[1024];
    int tid = threadIdx.x;
    s[tid] = (tid < nb) ? blockSums[tid] : 0;
    __syncthreads();
    for (int d = 1; d < 1024; d <<= 1) {
        int v = (tid >= d) ? s[tid - d] : 0;
        __syncthreads();
        s[tid] += v;
        __syncthreads();
    }
    if (tid < nb) blockOffs[tid] = (tid == 0) ? 0 : s[tid - 1];
    if (tid == 1023) offsets[N] = s[1023];
}

// K2c: in-block exclusive scan of 256 counts + block offset -> offsets; dinv = rsqrt(deg+1)
__global__ void scan_apply(const int* __restrict__ counts, const int* __restrict__ blockOffs,
                           int* __restrict__ offsets, float* __restrict__ dinv, int N) {
    __shared__ int s[256];
    int tid = threadIdx.x;
    int i = blockIdx.x * 256 + tid;
    int c = (i < N) ? counts[i] : 0;
    s[tid] = c;
    __syncthreads();
    for (int d = 1; d < 256; d <<= 1) {
        int v = (tid >= d) ? s[tid - d] : 0;
        __syncthreads();
        s[tid] += v;
        __syncthreads();
    }
    if (i < N) {
        offsets[i] = blockOffs[blockIdx.x] + s[tid] - c;  // exclusive
        dinv[i] = rsqrtf((float)(c + 1));                 // +1 self loop; deg >= 1
    }
}

// ---------------------------------------------------------------------------
// K3: scatter edge sources into CSR buckets
__global__ void scatter_kernel(const int* __restrict__ row, const int* __restrict__ col,
                               const int* __restrict__ offsets, int* __restrict__ cursor,
                               int* __restrict__ csr, int E) {
    int e = blockIdx.x * blockDim.x + threadIdx.x;
    if (e < E) {
        int c = col[e];
        int pos = offsets[c] + atomicAdd(&cursor[c], 1);
        csr[pos] = row[e];
    }
}

// ---------------------------------------------------------------------------
// K4: xs = fp16( (x @ W.T) * dinv[row] )  — W-RESIDENT, 8 rows x 4 cols / thread.
// launch_bounds(512,2) => 128-VGPR budget (R6: (512,4) => 64-VGPR cap, spilled
// 650 MB to scratch). 8 rows from GLOBAL broadcast x 4 cols from LDS keeps CU
// LDS demand at 0.75 of the pipe (R5's 4x4 was 1.5x -> capped at 34% VALU).
// XOR swizzle (k ^ ((j&31)<<2)) keeps float4 contiguity, 0 bank conflicts.
// fp16 output: halves gather's gathered bytes (R7: gather FETCH 145 MB).
__global__ __launch_bounds__(512, 2) void gemm_kernel(
    const float* __restrict__ x, const float* __restrict__ W,
    const float* __restrict__ dinv, __half* __restrict__ xsh, int N) {
    __shared__ float sw[128 * 128];  // 64 KB, element (j,k) at j*128 + (k ^ ((j&31)<<2))
    int tid = threadIdx.x;
    int c  = tid & 31;   // column lane: cols c + 32q
    int rg = tid >> 5;   // row group in [0,16): rows rg + 16i, i in [0,8)

    // stage W once: 4096 float4s, 8 per thread
#pragma unroll
    for (int t = 0; t < 8; ++t) {
        int idx = tid + t * 512;                   // [0,4096)
        int j = idx >> 5, k4 = idx & 31;           // j in [0,128), k4 in [0,32)
        float4 v = ((const float4*)W)[idx];
        *((float4*)&sw[j * 128 + ((k4 * 4) ^ ((j & 31) << 2))]) = v;
    }
    __syncthreads();

    int cswz = c << 2;  // swizzle offset for this lane's columns (j&31 == c for all q)
    int r0 = blockIdx.x * 128;

    const float4* xr[8];
    bool valid[8];
#pragma unroll
    for (int i = 0; i < 8; ++i) {
        int grow = r0 + rg + 16 * i;
        valid[i] = (grow < N);
        xr[i] = (const float4*)&x[(size_t)(valid[i] ? grow : 0) * 128];
    }

    float acc[8][4];
#pragma unroll
    for (int i = 0; i < 8; ++i)
#pragma unroll
        for (int q = 0; q < 4; ++q) acc[i][q] = 0.f;

#pragma unroll 4
    for (int k4 = 0; k4 < 32; ++k4) {
        float4 wv[4], xv[8];
#pragma unroll
        for (int q = 0; q < 4; ++q)
            wv[q] = *((const float4*)&sw[(c + 32 * q) * 128 + ((k4 * 4) ^ cswz)]);
#pragma unroll
        for (int i = 0; i < 8; ++i) xv[i] = xr[i][k4];
#pragma unroll
        for (int i = 0; i < 8; ++i)
#pragma unroll
            for (int q = 0; q < 4; ++q)
                acc[i][q] += xv[i].x * wv[q].x + xv[i].y * wv[q].y +
                             xv[i].z * wv[q].z + xv[i].w * wv[q].w;
    }

#pragma unroll
    for (int i = 0; i < 8; ++i) {
        int grow = r0 + rg + 16 * i;
        if (valid[i]) {
            float dv = dinv[grow];
#pragma unroll
            for (int q = 0; q < 4; ++q)
                xsh[(size_t)grow * 128 + c + 32 * q] = __float2half(acc[i][q] * dv);
        }
    }
}

// ---------------------------------------------------------------------------
// K5: gather aggregation + FUSED moments. One wave per node:
// pre[n] = dinv[n]*(xs[n] + sum xs[src]); lane owns cols {2*lane, 2*lane+1}
// so per-lane colsum partials + wave-reduced sumsq -> LDS -> 129 global
// atomics per block. Tail edges use predicated 8-deep loads (index-0
// fallback, L1-hot) so avg-degree-12 nodes keep full MLP.
__global__ void gather_kernel(const __half2* __restrict__ xs2, const float* __restrict__ dinv,
                              const int* __restrict__ offsets, const int* __restrict__ csr,
                              float* __restrict__ pre, float* __restrict__ colsum,
                              float* __restrict__ sumsq, int N) {
    __shared__ float scol[128];
    __shared__ float sss;
    if (threadIdx.x < 128) scol[threadIdx.x] = 0.f;
    if (threadIdx.x == 0) sss = 0.f;
    __syncthreads();

    int lane = threadIdx.x & 63;
    int wid = (blockIdx.x * blockDim.x + threadIdx.x) >> 6;
    int nw  = (gridDim.x * blockDim.x) >> 6;
    float2* pre2 = (float2*)pre;
    float csx = 0.f, csy = 0.f, ss = 0.f;

    for (int n = wid; n < N; n += nw) {
        int s = offsets[n], e = offsets[n + 1];
        float2 acc = __half22float2(xs2[n * 64 + lane]);  // self loop term
        for (int p = s; p < e; p += 8) {
            int idx[8]; bool v[8];
#pragma unroll
            for (int t = 0; t < 8; ++t) {
                v[t] = (p + t) < e;                // wave-uniform predicate
                idx[t] = v[t] ? csr[p + t] : 0;    // row 0 fallback: L1-hot, discarded
            }
            __half2 a[8];
#pragma unroll
            for (int t = 0; t < 8; ++t) a[t] = xs2[idx[t] * 64 + lane];
#pragma unroll
            for (int t = 0; t < 8; ++t) {
                float2 f = __half22float2(a[t]);
                if (v[t]) { acc.x += f.x; acc.y += f.y; }
            }
        }
        float dv = dinv[n];
        float vx = acc.x * dv, vy = acc.y * dv;
        pre2[n * 64 + lane] = make_float2(vx, vy);
        csx += vx; csy += vy; ss += vx * vx + vy * vy;
    }

    // block-level reduction: colsum via LDS atomics (4 waves hit 128 slots),
    // sumsq via wave shuffle then LDS atomic
    atomicAdd(&scol[2 * lane], csx);
    atomicAdd(&scol[2 * lane + 1], csy);
    for (int d = 32; d > 0; d >>= 1) ss += __shfl_down(ss, d);
    if (lane == 0) atomicAdd(&sss, ss);
    __syncthreads();
    if (threadIdx.x < 128) atomicAdd(&colsum[threadIdx.x], scol[threadIdx.x]);
    if (threadIdx.x == 128) atomicAdd(sumsq, sss);
}

// ---------------------------------------------------------------------------
// K8: FUSED params + apply. Each block redundantly derives m[j] and s from
// colsum/sumsq (129 L2-hot loads), then: y=(v-m_j)*s; out = y>0 ? 2y : y.
__global__ void final_kernel(float* __restrict__ out, const float* __restrict__ colsum,
                             const float* __restrict__ sumsq, int N, int total) {
    __shared__ float sm[128];
    __shared__ float red[128];
    __shared__ float sscale;
    int t = threadIdx.x;
    if (t < 128) {
        float m = colsum[t] / (float)N;
        sm[t] = m;
        red[t] = m * m;
    }
    __syncthreads();
    for (int d = 64; d > 0; d >>= 1) {
        if (t < d) red[t] += red[t + d];
        __syncthreads();
    }
    if (t == 0) {
        float tot = sumsq[0] - (float)N * red[0];  // sum (out - m)^2
        sscale = rsqrtf(EPS + tot / (float)N);
    }
    __syncthreads();
    float s = sscale;
    int tid = blockIdx.x * blockDim.x + threadIdx.x;
    int stride = gridDim.x * blockDim.x;
    for (int i = tid; i < total; i += stride) {
        float y = (out[i] - sm[i & 127]) * s;
        out[i] = y > 0.f ? 2.f * y : y;
    }
}

// ---------------------------------------------------------------------------
extern "C" void kernel_launch(void* const* d_in, const int* in_sizes, int n_in,
                              void* d_out, int out_size, void* d_ws, size_t ws_size,
                              hipStream_t stream) {
    const float* x = (const float*)d_in[0];
    const float* W = (const float*)d_in[1];
    const int* ei  = (const int*)d_in[2];
    int N = in_sizes[0] / 128;
    int E = in_sizes[2] / 2;
    const int* row = ei;        // edge_index[0] = source
    const int* col = ei + E;    // edge_index[1] = aggregation target
    float* out = (float*)d_out;

    int nb = (N + 255) / 256;   // scan blocks (196 for N=50000; must be <= 1024)

    // workspace layout (xs is fp16 = N*64 float-slots; rest 4-byte elements)
    __half* xsh      = (__half*)d_ws;           // N*128 halves
    float* dinv      = (float*)d_ws + (size_t)N * 64;  // N
    int*   counts    = (int*)(dinv + N);        // N    [zeroed]
    int*   cursor    = counts + N;              // N    [zeroed]
    float* colsum    = (float*)(cursor + N);    // 128  [zeroed]
    float* sumsq     = colsum + 128;            // 1    [zeroed]
    int*   offsets   = (int*)(sumsq + 1);       // N+1
    int*   csr       = offsets + (N + 1);       // E
    int*   blockSums = csr + E;                 // nb
    int*   blockOffs = blockSums + nb;          // nb

    hipMemsetAsync(counts, 0, (size_t)(2 * N + 129) * 4, stream);

    count_kernel  <<<(E + 255) / 256, 256, 0, stream>>>(col, counts, E);
    scan_reduce   <<<nb, 256, 0, stream>>>(counts, blockSums, N);
    scan_blocksums<<<1, 1024, 0, stream>>>(blockSums, blockOffs, nb, offsets, N);
    scan_apply    <<<nb, 256, 0, stream>>>(counts, blockOffs, offsets, dinv, N);
    scatter_kernel<<<(E + 255) / 256, 256, 0, stream>>>(row, col, offsets, cursor, csr, E);
    gemm_kernel   <<<(N + 127) / 128, 512, 0, stream>>>(x, W, dinv, xsh, N);
    gather_kernel <<<2048, 256, 0, stream>>>((const __half2*)xsh, dinv, offsets, csr,
                                             out, colsum, sumsq, N);
    final_kernel  <<<1024, 256, 0, stream>>>(out, colsum, sumsq, N, N * 128);
}

// Round 9
// 276.173 us; speedup vs baseline: 1.0228x; 1.0228x over previous
//
#include <hip/hip_runtime.h>
#include <hip/hip_fp16.h>

#define EPS 1e-5f

// ---------------------------------------------------------------------------
// K1: in-degree histogram (edges only; self-loop folded in as +1 later)
__global__ void count_kernel(const int* __restrict__ col, int* __restrict__ counts, int E) {
    int e = blockIdx.x * blockDim.x + threadIdx.x;
    if (e < E) atomicAdd(&counts[col[e]], 1);
}

// ---------------------------------------------------------------------------
// K2a: per-block (256 counts each) partial sums
__global__ void scan_reduce(const int* __restrict__ counts, int* __restrict__ blockSums, int N) {
    __shared__ int red[256];
    int i = blockIdx.x * 256 + threadIdx.x;
    red[threadIdx.x] = (i < N) ? counts[i] : 0;
    __syncthreads();
    for (int d = 128; d > 0; d >>= 1) {
        if (threadIdx.x < d) red[threadIdx.x] += red[threadIdx.x + d];
        __syncthreads();
    }
    if (threadIdx.x == 0) blockSums[blockIdx.x] = red[0];
}

// K2b: single-block exclusive scan over the (<=1024) block sums; writes offsets[N]=total
__global__ void scan_blocksums(int* __restrict__ blockSums, int* __restrict__ blockOffs,
                               int nb, int* __restrict__ offsets, int N) {
    __shared__ int s[1024];
    int tid = threadIdx.x;
    s[tid] = (tid < nb) ? blockSums[tid] : 0;
    __syncthreads();
    for (int d = 1; d < 1024; d <<= 1) {
        int v = (tid >= d) ? s[tid - d] : 0;
        __syncthreads();
        s[tid] += v;
        __syncthreads();
    }
    if (tid < nb) blockOffs[tid] = (tid == 0) ? 0 : s[tid - 1];
    if (tid == 1023) offsets[N] = s[1023];
}

// K2c: in-block exclusive scan of 256 counts + block offset -> offsets; dinv = rsqrt(deg+1)
__global__ void scan_apply(const int* __restrict__ counts, const int* __restrict__ blockOffs,
                           int* __restrict__ offsets, float* __restrict__ dinv, int N) {
    __shared__ int s[256];
    int tid = threadIdx.x;
    int i = blockIdx.x * 256 + tid;
    int c = (i < N) ? counts[i] : 0;
    s[tid] = c;
    __syncthreads();
    for (int d = 1; d < 256; d <<= 1) {
        int v = (tid >= d) ? s[tid - d] : 0;
        __syncthreads();
        s[tid] += v;
        __syncthreads();
    }
    if (i < N) {
        offsets[i] = blockOffs[blockIdx.x] + s[tid] - c;  // exclusive
        dinv[i] = rsqrtf((float)(c + 1));                 // +1 self loop; deg >= 1
    }
}

// ---------------------------------------------------------------------------
// K3: scatter edge sources into CSR buckets
__global__ void scatter_kernel(const int* __restrict__ row, const int* __restrict__ col,
                               const int* __restrict__ offsets, int* __restrict__ cursor,
                               int* __restrict__ csr, int E) {
    int e = blockIdx.x * blockDim.x + threadIdx.x;
    if (e < E) {
        int c = col[e];
        int pos = offsets[c] + atomicAdd(&cursor[c], 1);
        csr[pos] = row[e];
    }
}

// ---------------------------------------------------------------------------
// K4: xs = fp16( (x @ W.T) * dinv[row] )  — W-RESIDENT, 8 rows x 4 cols / thread.
// launch_bounds(512,2) => 128-VGPR budget (R6: (512,4) => 64-VGPR cap, spilled
// 650 MB to scratch). 8 rows from GLOBAL broadcast x 4 cols from LDS keeps CU
// LDS demand at 0.75 of the pipe (R5's 4x4 was 1.5x -> capped at 34% VALU).
// XOR swizzle (k ^ ((j&31)<<2)) keeps float4 contiguity, 0 bank conflicts.
// fp16 output: halves gather's gathered bytes (R7->R8: FETCH 145 -> 65.7 MB).
__global__ __launch_bounds__(512, 2) void gemm_kernel(
    const float* __restrict__ x, const float* __restrict__ W,
    const float* __restrict__ dinv, __half* __restrict__ xsh, int N) {
    __shared__ float sw[128 * 128];  // 64 KB, element (j,k) at j*128 + (k ^ ((j&31)<<2))
    int tid = threadIdx.x;
    int c  = tid & 31;   // column lane: cols c + 32q
    int rg = tid >> 5;   // row group in [0,16): rows rg + 16i, i in [0,8)

    // stage W once: 4096 float4s, 8 per thread
#pragma unroll
    for (int t = 0; t < 8; ++t) {
        int idx = tid + t * 512;                   // [0,4096)
        int j = idx >> 5, k4 = idx & 31;           // j in [0,128), k4 in [0,32)
        float4 v = ((const float4*)W)[idx];
        *((float4*)&sw[j * 128 + ((k4 * 4) ^ ((j & 31) << 2))]) = v;
    }
    __syncthreads();

    int cswz = c << 2;  // swizzle offset for this lane's columns (j&31 == c for all q)
    int r0 = blockIdx.x * 128;

    const float4* xr[8];
    bool valid[8];
#pragma unroll
    for (int i = 0; i < 8; ++i) {
        int grow = r0 + rg + 16 * i;
        valid[i] = (grow < N);
        xr[i] = (const float4*)&x[(size_t)(valid[i] ? grow : 0) * 128];
    }

    float acc[8][4];
#pragma unroll
    for (int i = 0; i < 8; ++i)
#pragma unroll
        for (int q = 0; q < 4; ++q) acc[i][q] = 0.f;

#pragma unroll 4
    for (int k4 = 0; k4 < 32; ++k4) {
        float4 wv[4], xv[8];
#pragma unroll
        for (int q = 0; q < 4; ++q)
            wv[q] = *((const float4*)&sw[(c + 32 * q) * 128 + ((k4 * 4) ^ cswz)]);
#pragma unroll
        for (int i = 0; i < 8; ++i) xv[i] = xr[i][k4];
#pragma unroll
        for (int i = 0; i < 8; ++i)
#pragma unroll
            for (int q = 0; q < 4; ++q)
                acc[i][q] += xv[i].x * wv[q].x + xv[i].y * wv[q].y +
                             xv[i].z * wv[q].z + xv[i].w * wv[q].w;
    }

#pragma unroll
    for (int i = 0; i < 8; ++i) {
        int grow = r0 + rg + 16 * i;
        if (valid[i]) {
            float dv = dinv[grow];
#pragma unroll
            for (int q = 0; q < 4; ++q)
                xsh[(size_t)grow * 128 + c + 32 * q] = __float2half(acc[i][q] * dv);
        }
    }
}

// ---------------------------------------------------------------------------
// K5: gather aggregation + FUSED moments. One wave per node.
// R8 post-mortem: predicated 8-wide tail chunks made the loop instruction-
// bound (VALUBusy 12->21%, dur 53->81us despite halved bytes). Reverted to
// the R7 loop shape: unpredicated 8-deep main loop + scalar tail. fp16 loads
// kept (bytes halved). Moments fused as block epilogue (cheap, once/block).
__global__ void gather_kernel(const __half2* __restrict__ xs2, const float* __restrict__ dinv,
                              const int* __restrict__ offsets, const int* __restrict__ csr,
                              float* __restrict__ pre, float* __restrict__ colsum,
                              float* __restrict__ sumsq, int N) {
    __shared__ float scol[128];
    __shared__ float sss;
    if (threadIdx.x < 128) scol[threadIdx.x] = 0.f;
    if (threadIdx.x == 0) sss = 0.f;
    __syncthreads();

    int lane = threadIdx.x & 63;
    int wid = (blockIdx.x * blockDim.x + threadIdx.x) >> 6;
    int nw  = (gridDim.x * blockDim.x) >> 6;
    float2* pre2 = (float2*)pre;
    float csx = 0.f, csy = 0.f, ss = 0.f;

    for (int n = wid; n < N; n += nw) {
        int s = offsets[n], e = offsets[n + 1];
        float2 acc = __half22float2(xs2[n * 64 + lane]);  // self loop term
        int p = s;
        for (; p + 8 <= e; p += 8) {      // 8-deep ILP on the random gathers
            int idx[8];
#pragma unroll
            for (int t = 0; t < 8; ++t) idx[t] = csr[p + t];
            __half2 a[8];
#pragma unroll
            for (int t = 0; t < 8; ++t) a[t] = xs2[idx[t] * 64 + lane];
#pragma unroll
            for (int t = 0; t < 8; ++t) {
                float2 f = __half22float2(a[t]);
                acc.x += f.x; acc.y += f.y;
            }
        }
        for (; p < e; ++p) {
            float2 f = __half22float2(xs2[csr[p] * 64 + lane]);
            acc.x += f.x; acc.y += f.y;
        }
        float dv = dinv[n];
        float vx = acc.x * dv, vy = acc.y * dv;
        pre2[n * 64 + lane] = make_float2(vx, vy);
        csx += vx; csy += vy; ss += vx * vx + vy * vy;
    }

    // block-level reduction: colsum via LDS atomics (4 waves hit 128 slots),
    // sumsq via wave shuffle then LDS atomic; one global atomic per slot/block
    atomicAdd(&scol[2 * lane], csx);
    atomicAdd(&scol[2 * lane + 1], csy);
    for (int d = 32; d > 0; d >>= 1) ss += __shfl_down(ss, d);
    if (lane == 0) atomicAdd(&sss, ss);
    __syncthreads();
    if (threadIdx.x < 128) atomicAdd(&colsum[threadIdx.x], scol[threadIdx.x]);
    if (threadIdx.x == 128) atomicAdd(sumsq, sss);
}

// ---------------------------------------------------------------------------
// K8: FUSED params + apply. Each block redundantly derives m[j] and s from
// colsum/sumsq (129 L2-hot loads), then: y=(v-m_j)*s; out = y>0 ? 2y : y.
__global__ void final_kernel(float* __restrict__ out, const float* __restrict__ colsum,
                             const float* __restrict__ sumsq, int N, int total) {
    __shared__ float sm[128];
    __shared__ float red[128];
    __shared__ float sscale;
    int t = threadIdx.x;
    if (t < 128) {
        float m = colsum[t] / (float)N;
        sm[t] = m;
        red[t] = m * m;
    }
    __syncthreads();
    for (int d = 64; d > 0; d >>= 1) {
        if (t < d) red[t] += red[t + d];
        __syncthreads();
    }
    if (t == 0) {
        float tot = sumsq[0] - (float)N * red[0];  // sum (out - m)^2
        sscale = rsqrtf(EPS + tot / (float)N);
    }
    __syncthreads();
    float s = sscale;
    int tid = blockIdx.x * blockDim.x + threadIdx.x;
    int stride = gridDim.x * blockDim.x;
    for (int i = tid; i < total; i += stride) {
        float y = (out[i] - sm[i & 127]) * s;
        out[i] = y > 0.f ? 2.f * y : y;
    }
}

// ---------------------------------------------------------------------------
extern "C" void kernel_launch(void* const* d_in, const int* in_sizes, int n_in,
                              void* d_out, int out_size, void* d_ws, size_t ws_size,
                              hipStream_t stream) {
    const float* x = (const float*)d_in[0];
    const float* W = (const float*)d_in[1];
    const int* ei  = (const int*)d_in[2];
    int N = in_sizes[0] / 128;
    int E = in_sizes[2] / 2;
    const int* row = ei;        // edge_index[0] = source
    const int* col = ei + E;    // edge_index[1] = aggregation target
    float* out = (float*)d_out;

    int nb = (N + 255) / 256;   // scan blocks (196 for N=50000; must be <= 1024)

    // workspace layout (xs is fp16 = N*64 float-slots; rest 4-byte elements)
    __half* xsh      = (__half*)d_ws;           // N*128 halves
    float* dinv      = (float*)d_ws + (size_t)N * 64;  // N
    int*   counts    = (int*)(dinv + N);        // N    [zeroed]
    int*   cursor    = counts + N;              // N    [zeroed]
    float* colsum    = (float*)(cursor + N);    // 128  [zeroed]
    float* sumsq     = colsum + 128;            // 1    [zeroed]
    int*   offsets   = (int*)(sumsq + 1);       // N+1
    int*   csr       = offsets + (N + 1);       // E
    int*   blockSums = csr + E;                 // nb
    int*   blockOffs = blockSums + nb;          // nb

    hipMemsetAsync(counts, 0, (size_t)(2 * N + 129) * 4, stream);

    count_kernel  <<<(E + 255) / 256, 256, 0, stream>>>(col, counts, E);
    scan_reduce   <<<nb, 256, 0, stream>>>(counts, blockSums, N);
    scan_blocksums<<<1, 1024, 0, stream>>>(blockSums, blockOffs, nb, offsets, N);
    scan_apply    <<<nb, 256, 0, stream>>>(counts, blockOffs, offsets, dinv, N);
    scatter_kernel<<<(E + 255) / 256, 256, 0, stream>>>(row, col, offsets, cursor, csr, E);
    gemm_kernel   <<<(N + 127) / 128, 512, 0, stream>>>(x, W, dinv, xsh, N);
    gather_kernel <<<2048, 256, 0, stream>>>((const __half2*)xsh, dinv, offsets, csr,
                                             out, colsum, sumsq, N);
    final_kernel  <<<1024, 256, 0, stream>>>(out, colsum, sumsq, N, N * 128);
}

// Round 10
// 248.071 us; speedup vs baseline: 1.1386x; 1.1133x over previous
//
#include <hip/hip_runtime.h>
#include <hip/hip_fp16.h>

#define EPS 1e-5f
#define NREP 16       // colsum/sumsq replicas (breaks the R8/R9 atomic storm)
#define REPSTRIDE 132 // floats per replica row; 132 % 16 = 4 staggers L2 lines

// ---------------------------------------------------------------------------
// K1: in-degree histogram (edges only; self-loop folded in as +1 later)
__global__ void count_kernel(const int* __restrict__ col, int* __restrict__ counts, int E) {
    int e = blockIdx.x * blockDim.x + threadIdx.x;
    if (e < E) atomicAdd(&counts[col[e]], 1);
}

// ---------------------------------------------------------------------------
// K2a: per-block (256 counts each) partial sums
__global__ void scan_reduce(const int* __restrict__ counts, int* __restrict__ blockSums, int N) {
    __shared__ int red[256];
    int i = blockIdx.x * 256 + threadIdx.x;
    red[threadIdx.x] = (i < N) ? counts[i] : 0;
    __syncthreads();
    for (int d = 128; d > 0; d >>= 1) {
        if (threadIdx.x < d) red[threadIdx.x] += red[threadIdx.x + d];
        __syncthreads();
    }
    if (threadIdx.x == 0) blockSums[blockIdx.x] = red[0];
}

// K2b: single-block exclusive scan over the (<=1024) block sums; writes offsets[N]=total
__global__ void scan_blocksums(int* __restrict__ blockSums, int* __restrict__ blockOffs,
                               int nb, int* __restrict__ offsets, int N) {
    __shared__ int s[1024];
    int tid = threadIdx.x;
    s[tid] = (tid < nb) ? blockSums[tid] : 0;
    __syncthreads();
    for (int d = 1; d < 1024; d <<= 1) {
        int v = (tid >= d) ? s[tid - d] : 0;
        __syncthreads();
        s[tid] += v;
        __syncthreads();
    }
    if (tid < nb) blockOffs[tid] = (tid == 0) ? 0 : s[tid - 1];
    if (tid == 1023) offsets[N] = s[1023];
}

// K2c: in-block exclusive scan of 256 counts + block offset -> offsets; dinv = rsqrt(deg+1)
__global__ void scan_apply(const int* __restrict__ counts, const int* __restrict__ blockOffs,
                           int* __restrict__ offsets, float* __restrict__ dinv, int N) {
    __shared__ int s[256];
    int tid = threadIdx.x;
    int i = blockIdx.x * 256 + tid;
    int c = (i < N) ? counts[i] : 0;
    s[tid] = c;
    __syncthreads();
    for (int d = 1; d < 256; d <<= 1) {
        int v = (tid >= d) ? s[tid - d] : 0;
        __syncthreads();
        s[tid] += v;
        __syncthreads();
    }
    if (i < N) {
        offsets[i] = blockOffs[blockIdx.x] + s[tid] - c;  // exclusive
        dinv[i] = rsqrtf((float)(c + 1));                 // +1 self loop; deg >= 1
    }
}

// ---------------------------------------------------------------------------
// K3: scatter edge sources into CSR buckets
__global__ void scatter_kernel(const int* __restrict__ row, const int* __restrict__ col,
                               const int* __restrict__ offsets, int* __restrict__ cursor,
                               int* __restrict__ csr, int E) {
    int e = blockIdx.x * blockDim.x + threadIdx.x;
    if (e < E) {
        int c = col[e];
        int pos = offsets[c] + atomicAdd(&cursor[c], 1);
        csr[pos] = row[e];
    }
}

// ---------------------------------------------------------------------------
// K4: xs = fp16( (x @ W.T) * dinv[row] )  — W-RESIDENT, 8 rows x 4 cols / thread.
// launch_bounds(512,2) => 128-VGPR budget (R6: (512,4) => 64-VGPR cap, spilled
// 650 MB to scratch). 8 rows from GLOBAL broadcast x 4 cols from LDS keeps CU
// LDS demand at 0.75 of the pipe (R5's 4x4 was 1.5x -> capped at 34% VALU).
// XOR swizzle (k ^ ((j&31)<<2)) keeps float4 contiguity, 0 bank conflicts.
__global__ __launch_bounds__(512, 2) void gemm_kernel(
    const float* __restrict__ x, const float* __restrict__ W,
    const float* __restrict__ dinv, __half* __restrict__ xsh, int N) {
    __shared__ float sw[128 * 128];  // 64 KB, element (j,k) at j*128 + (k ^ ((j&31)<<2))
    int tid = threadIdx.x;
    int c  = tid & 31;   // column lane: cols c + 32q
    int rg = tid >> 5;   // row group in [0,16): rows rg + 16i, i in [0,8)

    // stage W once: 4096 float4s, 8 per thread
#pragma unroll
    for (int t = 0; t < 8; ++t) {
        int idx = tid + t * 512;                   // [0,4096)
        int j = idx >> 5, k4 = idx & 31;           // j in [0,128), k4 in [0,32)
        float4 v = ((const float4*)W)[idx];
        *((float4*)&sw[j * 128 + ((k4 * 4) ^ ((j & 31) << 2))]) = v;
    }
    __syncthreads();

    int cswz = c << 2;  // swizzle offset for this lane's columns (j&31 == c for all q)
    int r0 = blockIdx.x * 128;

    const float4* xr[8];
    bool valid[8];
#pragma unroll
    for (int i = 0; i < 8; ++i) {
        int grow = r0 + rg + 16 * i;
        valid[i] = (grow < N);
        xr[i] = (const float4*)&x[(size_t)(valid[i] ? grow : 0) * 128];
    }

    float acc[8][4];
#pragma unroll
    for (int i = 0; i < 8; ++i)
#pragma unroll
        for (int q = 0; q < 4; ++q) acc[i][q] = 0.f;

#pragma unroll 4
    for (int k4 = 0; k4 < 32; ++k4) {
        float4 wv[4], xv[8];
#pragma unroll
        for (int q = 0; q < 4; ++q)
            wv[q] = *((const float4*)&sw[(c + 32 * q) * 128 + ((k4 * 4) ^ cswz)]);
#pragma unroll
        for (int i = 0; i < 8; ++i) xv[i] = xr[i][k4];
#pragma unroll
        for (int i = 0; i < 8; ++i)
#pragma unroll
            for (int q = 0; q < 4; ++q)
                acc[i][q] += xv[i].x * wv[q].x + xv[i].y * wv[q].y +
                             xv[i].z * wv[q].z + xv[i].w * wv[q].w;
    }

#pragma unroll
    for (int i = 0; i < 8; ++i) {
        int grow = r0 + rg + 16 * i;
        if (valid[i]) {
            float dv = dinv[grow];
#pragma unroll
            for (int q = 0; q < 4; ++q)
                xsh[(size_t)grow * 128 + c + 32 * q] = __float2half(acc[i][q] * dv);
        }
    }
}

// ---------------------------------------------------------------------------
// K5: gather aggregation + fused moments (REPLICATED accumulators).
// R9 post-mortem: 2048 blocks x 129 atomics onto ONE copy of colsum/sumsq =
// 2048-deep serialized RMW chains -> ~25us atomic-storm tail (R7 separate
// moments kernel had 128 blocks and ran 53us; R8/R9 fused = 78-81us). Fix:
// 16 replicas indexed blockIdx&15 -> 128-deep chains. Also: 4-wide mid batch
// between the 8-wide main loop and scalar tail (deg-12 node: 4 serialized
// vmcnt(0) loads -> 0..3).
__global__ void gather_kernel(const __half2* __restrict__ xs2, const float* __restrict__ dinv,
                              const int* __restrict__ offsets, const int* __restrict__ csr,
                              float* __restrict__ pre, float* __restrict__ colrep,
                              float* __restrict__ ssrep, int N) {
    __shared__ float scol[128];
    __shared__ float sss;
    if (threadIdx.x < 128) scol[threadIdx.x] = 0.f;
    if (threadIdx.x == 0) sss = 0.f;
    __syncthreads();

    int lane = threadIdx.x & 63;
    int wid = (blockIdx.x * blockDim.x + threadIdx.x) >> 6;
    int nw  = (gridDim.x * blockDim.x) >> 6;
    float2* pre2 = (float2*)pre;
    float csx = 0.f, csy = 0.f, ss = 0.f;

    for (int n = wid; n < N; n += nw) {
        int s = offsets[n], e = offsets[n + 1];
        float2 acc = __half22float2(xs2[n * 64 + lane]);  // self loop term
        int p = s;
        for (; p + 8 <= e; p += 8) {      // 8-deep ILP on the random gathers
            int idx[8];
#pragma unroll
            for (int t = 0; t < 8; ++t) idx[t] = csr[p + t];
            __half2 a[8];
#pragma unroll
            for (int t = 0; t < 8; ++t) a[t] = xs2[idx[t] * 64 + lane];
#pragma unroll
            for (int t = 0; t < 8; ++t) {
                float2 f = __half22float2(a[t]);
                acc.x += f.x; acc.y += f.y;
            }
        }
        if (p + 4 <= e) {                 // 4-wide mid batch
            int idx[4];
#pragma unroll
            for (int t = 0; t < 4; ++t) idx[t] = csr[p + t];
            __half2 a[4];
#pragma unroll
            for (int t = 0; t < 4; ++t) a[t] = xs2[idx[t] * 64 + lane];
#pragma unroll
            for (int t = 0; t < 4; ++t) {
                float2 f = __half22float2(a[t]);
                acc.x += f.x; acc.y += f.y;
            }
            p += 4;
        }
        for (; p < e; ++p) {              // <=3 serial stragglers
            float2 f = __half22float2(xs2[csr[p] * 64 + lane]);
            acc.x += f.x; acc.y += f.y;
        }
        float dv = dinv[n];
        float vx = acc.x * dv, vy = acc.y * dv;
        pre2[n * 64 + lane] = make_float2(vx, vy);
        csx += vx; csy += vy; ss += vx * vx + vy * vy;
    }

    // block-level reduction, then one atomic per slot into replica blockIdx&15
    atomicAdd(&scol[2 * lane], csx);
    atomicAdd(&scol[2 * lane + 1], csy);
    for (int d = 32; d > 0; d >>= 1) ss += __shfl_down(ss, d);
    if (lane == 0) atomicAdd(&sss, ss);
    __syncthreads();
    int rep = blockIdx.x & (NREP - 1);
    if (threadIdx.x < 128) atomicAdd(&colrep[rep * REPSTRIDE + threadIdx.x], scol[threadIdx.x]);
    if (threadIdx.x == 128) atomicAdd(&ssrep[rep], sss);
}

// ---------------------------------------------------------------------------
// K8: FUSED params + apply. Each block sums the 16 replicas to derive m[j]
// and s (all L2-hot), then: y=(v-m_j)*s; out = y>0 ? 2y : y.
__global__ void final_kernel(float* __restrict__ out, const float* __restrict__ colrep,
                             const float* __restrict__ ssrep, int N, int total) {
    __shared__ float sm[128];
    __shared__ float red[128];
    __shared__ float sscale;
    int t = threadIdx.x;
    if (t < 128) {
        float cs = 0.f;
#pragma unroll
        for (int r = 0; r < NREP; ++r) cs += colrep[r * REPSTRIDE + t];
        float m = cs / (float)N;
        sm[t] = m;
        red[t] = m * m;
    }
    __syncthreads();
    for (int d = 64; d > 0; d >>= 1) {
        if (t < d) red[t] += red[t + d];
        __syncthreads();
    }
    if (t == 0) {
        float sq = 0.f;
#pragma unroll
        for (int r = 0; r < NREP; ++r) sq += ssrep[r];
        float tot = sq - (float)N * red[0];  // sum (out - m)^2
        sscale = rsqrtf(EPS + tot / (float)N);
    }
    __syncthreads();
    float s = sscale;
    int tid = blockIdx.x * blockDim.x + threadIdx.x;
    int stride = gridDim.x * blockDim.x;
    for (int i = tid; i < total; i += stride) {
        float y = (out[i] - sm[i & 127]) * s;
        out[i] = y > 0.f ? 2.f * y : y;
    }
}

// ---------------------------------------------------------------------------
extern "C" void kernel_launch(void* const* d_in, const int* in_sizes, int n_in,
                              void* d_out, int out_size, void* d_ws, size_t ws_size,
                              hipStream_t stream) {
    const float* x = (const float*)d_in[0];
    const float* W = (const float*)d_in[1];
    const int* ei  = (const int*)d_in[2];
    int N = in_sizes[0] / 128;
    int E = in_sizes[2] / 2;
    const int* row = ei;        // edge_index[0] = source
    const int* col = ei + E;    // edge_index[1] = aggregation target
    float* out = (float*)d_out;

    int nb = (N + 255) / 256;   // scan blocks (196 for N=50000; must be <= 1024)

    // workspace layout (xs is fp16 = N*64 float-slots; rest 4-byte elements)
    __half* xsh      = (__half*)d_ws;                  // N*128 halves
    float* dinv      = (float*)d_ws + (size_t)N * 64;  // N
    int*   counts    = (int*)(dinv + N);               // N            [zeroed]
    int*   cursor    = counts + N;                     // N            [zeroed]
    float* colrep    = (float*)(cursor + N);           // NREP*REPSTRIDE [zeroed]
    float* ssrep     = colrep + NREP * REPSTRIDE;      // NREP         [zeroed]
    int*   offsets   = (int*)(ssrep + NREP);           // N+1
    int*   csr       = offsets + (N + 1);              // E
    int*   blockSums = csr + E;                        // nb
    int*   blockOffs = blockSums + nb;                 // nb

    hipMemsetAsync(counts, 0, (size_t)(2 * N + NREP * REPSTRIDE + NREP) * 4, stream);

    count_kernel  <<<(E + 255) / 256, 256, 0, stream>>>(col, counts, E);
    scan_reduce   <<<nb, 256, 0, stream>>>(counts, blockSums, N);
    scan_blocksums<<<1, 1024, 0, stream>>>(blockSums, blockOffs, nb, offsets, N);
    scan_apply    <<<nb, 256, 0, stream>>>(counts, blockOffs, offsets, dinv, N);
    scatter_kernel<<<(E + 255) / 256, 256, 0, stream>>>(row, col, offsets, cursor, csr, E);
    gemm_kernel   <<<(N + 127) / 128, 512, 0, stream>>>(x, W, dinv, xsh, N);
    gather_kernel <<<2048, 256, 0, stream>>>((const __half2*)xsh, dinv, offsets, csr,
                                             out, colrep, ssrep, N);
    final_kernel  <<<1024, 256, 0, stream>>>(out, colrep, ssrep, N, N * 128);
}